// Round 13
// baseline (501.241 us; speedup 1.0000x reference)
//
#include <hip/hip_runtime.h>
#include <stdint.h>

// B = 1048576 rows, HID = 64. Residual MLP with training-mode BatchNorm.
// Recompute-fused layer kernels + bf16 activations (128 MB in d_ws).
// Round 17 = R16 resubmitted verbatim (previous bench died with an infra
// error "MI355X container failed twice" before producing any measurement).
// Each WAVE processes TWO 32-row tiles: both tiles prefetched up-front via
// gld_lds (8 in-flight loads/wave), constants + W-fragments loaded once per
// wave, stats combined in LDS. 8192 blocks x 128 threads (2 waves).
// HARD RULES from measurement:
//   (1) keep the 32-row wave (R13: 16-row waves -> HBM 1.4TB/s, 68% slower).
//   (2) occupancy is pinned by the unified VGPR+AGPR footprint (~38% at
//       ~60 VGPR + 32-reg acc); block shape does NOT move it (R15). Avoid
//       any change adding persistent VGPRs (64-cliff: R8/R9).
//   (3) atomic same-address RMW ~60ns serialized (R6): <=64 contenders max.
//   (4) NEVER __threadfence() in per-block hot paths (R11: 6.7x disaster).
// MFMA 16x16x32 bf16 layouts (verified gfx950 mappings):
//   A: row = lane&15, k = (lane>>4)*8 + j   (16B contiguous -> b128)
//   B: col = lane&15, k = (lane>>4)*8 + j   (load from W^T, row-major)
//   C/D: col = lane&15, row = (lane>>4)*4 + reg

#define NROWS 1048576
#define EPS 1e-5f
#define INV_B 9.5367431640625e-07f  // 1/2^20 exact
#define LOG2E2 2.885390081777927f   // 2*log2(e)
#define BIGGRID 8192                // 8192 blocks x 128 rows (2 tiles)
#define NBUCKET 256

typedef __attribute__((ext_vector_type(8))) short bfrag;   // 8 bf16 = 4 VGPR
typedef __attribute__((ext_vector_type(4))) float facc;    // MFMA C/D
typedef __attribute__((ext_vector_type(4))) float f4v;
typedef unsigned int u32;

__device__ __forceinline__ float bf2f(short s) {
  union { unsigned u; float f; } v;
  v.u = ((unsigned)(unsigned short)s) << 16;
  return v.f;
}
__device__ __forceinline__ short f2bf(float f) {
  union { float f; unsigned u; } v;
  v.f = f;
  unsigned r = v.u + 0x7FFFu + ((v.u >> 16) & 1u);  // RNE
  return (short)(r >> 16);
}
// packed RNE f32->bf16x2 (identical rounding to f2bf, 1 instr for 2 elems)
__device__ __forceinline__ unsigned cvt_pk_bf16(float lo, float hi) {
  unsigned r;
  asm("v_cvt_pk_bf16_f32 %0, %1, %2" : "=v"(r) : "v"(lo), "v"(hi));
  return r;
}
// tanh = 1 - 2/(e^{2x}+1); v_exp + v_rcp, saturates correctly at +-inf
__device__ __forceinline__ float tanh_fast(float x) {
  float e = __builtin_amdgcn_exp2f(x * LOG2E2);
  return 1.f - 2.f * __builtin_amdgcn_rcpf(e + 1.f);
}
// async global -> LDS, 16 bytes/lane; LDS dest = uniform base + lane*16
__device__ __forceinline__ void gld16(const void* g, void* l) {
  __builtin_amdgcn_global_load_lds(
      (const __attribute__((address_space(1))) u32*)g,
      (__attribute__((address_space(3))) u32*)l, 16, 0, 0);
}
// swizzled short-index into linear [64][64] bf16 tile (128B rows):
// 16B unit u_phys = u_log ^ (row&7); content pre-swizzled at staging by
// permuting the per-lane GLOBAL source address (gld_lds dest is linear).
__device__ __forceinline__ int ysw(int r, int c) {
  return (r << 6) + ((((c >> 3) ^ (r & 7)) << 3) | (c & 7));
}

// ---------------- reduce: P[nb][W] -> atomicAdd into S[W] ----------------
template <int W>
__global__ __launch_bounds__(256) void k_reduce(const float* __restrict__ P,
                                                float* __restrict__ S,
                                                int rows_per_blk) {
  __shared__ float red[256];
  const int tid = threadIdx.x;
  const int col = tid % W;
  const int grp = tid / W;
  const int G = 256 / W;
  size_t r0 = (size_t)blockIdx.x * rows_per_blk;
  float s = 0.f;
  for (int r = grp; r < rows_per_blk; r += G) s += P[(r0 + r) * W + col];
  red[tid] = s;
  __syncthreads();
  if (tid < W) {
    float t = 0.f;
#pragma unroll 4
    for (int g = 0; g < G; ++g) t += red[g * W + tid];
    atomicAdd(&S[tid], t);
  }
}

// ---------------- small kernels ----------------

// Column sums/sumsq of x -> P[bid][8]. Blocks 0..63 also transpose Wh -> WT.
__global__ __launch_bounds__(256) void k_stats_x(const float* __restrict__ x,
                                                 const float* __restrict__ Wh,
                                                 short* __restrict__ WT,
                                                 float* __restrict__ P) {
  __shared__ float red[4][8];
  const int tid = threadIdx.x;
  const int wave = tid >> 6;
  const int bid = blockIdx.x;

  if (bid < 64) {  // folded k_prep: 64 blocks x 256 threads = 16384 elems
    int idx = bid * 256 + tid;
    int l = idx >> 12, rem = idx & 4095, k = rem >> 6, c = rem & 63;
    WT[l * 4096 + c * 64 + k] = f2bf(Wh[l * 4096 + k * 64 + c]);
  }

  size_t base = (size_t)bid * 1024 + tid;
  float s[4] = {0.f, 0.f, 0.f, 0.f}, q[4] = {0.f, 0.f, 0.f, 0.f};
#pragma unroll
  for (int it = 0; it < 4; ++it) {
    f4v v = *(const f4v*)(x + (base + (size_t)it * 256) * 4);
#pragma unroll
    for (int k = 0; k < 4; ++k) { s[k] += v[k]; q[k] = fmaf(v[k], v[k], q[k]); }
  }
#pragma unroll
  for (int off = 32; off > 0; off >>= 1) {
#pragma unroll
    for (int k = 0; k < 4; ++k) {
      s[k] += __shfl_xor(s[k], off);
      q[k] += __shfl_xor(q[k], off);
    }
  }
  if ((tid & 63) == 0) {
#pragma unroll
    for (int k = 0; k < 4; ++k) { red[wave][k] = s[k]; red[wave][4 + k] = q[k]; }
  }
  __syncthreads();
  if (tid < 8)
    P[bid * 8 + tid] = red[0][tid] + red[1][tid] + red[2][tid] + red[3][tid];
}

// Stats of z1 = tanh(bn0(x)@W0+b0) -> P[bid][128]. 2048 blocks, 128 rows/wave.
__global__ __launch_bounds__(256) void k_stats_z1(
    const float* __restrict__ x, const float* __restrict__ bn0g,
    const float* __restrict__ bn0b, const float* __restrict__ W0,
    const float* __restrict__ b0, const float* __restrict__ sx,
    float* __restrict__ P) {
  __shared__ float red[2][4][64];
  const int tid = threadIdx.x;
  const int lane = tid & 63;
  const int wave = tid >> 6;
  int gw = blockIdx.x * 4 + wave;
  float sc[4], sh[4];
#pragma unroll
  for (int k = 0; k < 4; ++k) {
    float mean = sx[k] * INV_B;
    float var = fmaf(-mean, mean, sx[4 + k] * INV_B);
    float rs = rsqrtf(var + EPS);
    sc[k] = bn0g[k] * rs;
    sh[k] = fmaf(-sc[k], mean, bn0b[k]);
  }
  // fold bn0 affine into the weight column: acc = b2 + sum_k x[k]*w2[k]
  float w2[4];
  float b2 = b0[lane];
#pragma unroll
  for (int k = 0; k < 4; ++k) {
    float w = W0[k * 64 + lane];
    w2[k] = sc[k] * w;
    b2 = fmaf(sh[k], w, b2);
  }
  float s = 0.f, q = 0.f;
  size_t r0 = (size_t)gw * 128;
  for (int r = 0; r < 128; ++r) {
    f4v xv = *(const f4v*)(x + (r0 + r) * 4);
    float acc = b2;
#pragma unroll
    for (int k = 0; k < 4; ++k) acc = fmaf(xv[k], w2[k], acc);
    float z = tanh_fast(acc);
    s += z;
    q = fmaf(z, z, q);
  }
  red[0][wave][lane] = s;
  red[1][wave][lane] = q;
  __syncthreads();
  if (tid < 128) {
    int which = tid >> 6, c = tid & 63;
    P[blockIdx.x * 128 + tid] = red[which][0][c] + red[which][1][c] +
                                red[which][2][c] + red[which][3][c];
  }
}

// ------- big fused kernels: 128 rows/block, 2 waves x 2 tiles of 32 rows ---

// K_first: Y1 = BN(tanh(bn0(x)@W0+b0)), write Y1 bf16,
// partial stats of Z2 = tanh(Y1 @ W_hid0 + b_hid0) -> bucket atomicAdd
__global__ __launch_bounds__(128) void k_first(
    const float* __restrict__ x, const float* __restrict__ bn0g,
    const float* __restrict__ bn0b, const float* __restrict__ W0,
    const float* __restrict__ b0, const float* __restrict__ gamma0,
    const float* __restrict__ beta0, const float* __restrict__ sx,
    const float* __restrict__ s1, const short* __restrict__ WTb,
    const float* __restrict__ bb, float* __restrict__ Pb,
    short* __restrict__ Y) {
  __shared__ __align__(16) float lds_x[2][64 * 4];
  __shared__ __align__(16) short lds_y[64 * 72];  // reused per tile
  __shared__ float red[2][128];

  const int tid = threadIdx.x;
  const int lane = tid & 63;
  const int wave = tid >> 6;
  const int l15 = lane & 15;
  const int q = lane >> 4;
  const int wr = wave * 32;
  const size_t r0 = (size_t)blockIdx.x * 128;

  // async prefetch of BOTH x tiles (lanes 0..31 per wave)
  if (lane < 32) {
#pragma unroll
    for (int b = 0; b < 2; ++b)
      gld16(x + (r0 + b * 64 + wr + lane) * 4, &lds_x[b][wr * 4]);
  }

  float sc0[4], sh0[4];
#pragma unroll
  for (int k = 0; k < 4; ++k) {
    float mean = sx[k] * INV_B;
    float var = fmaf(-mean, mean, sx[4 + k] * INV_B);
    float rs = rsqrtf(var + EPS);
    sc0[k] = bn0g[k] * rs;
    sh0[k] = fmaf(-sc0[k], mean, bn0b[k]);
  }
  // fold bn0 affine into weight column (same op order as k_stats_z1)
  float w2[4];
  float b2 = b0[lane];
#pragma unroll
  for (int k = 0; k < 4; ++k) {
    float w = W0[k * 64 + lane];
    w2[k] = sc0[k] * w;
    b2 = fmaf(sh0[k], w, b2);
  }
  float mean1 = s1[lane] * INV_B;
  float var1 = fmaf(-mean1, mean1, s1[64 + lane] * INV_B);
  float A1c = gamma0[lane] * rsqrtf(var1 + EPS);
  float B1c = fmaf(-A1c, mean1, beta0[lane]);
  float bbv[4];
  bfrag bwb[4][2];
#pragma unroll
  for (int nt = 0; nt < 4; ++nt) {
    bbv[nt] = bb[nt * 16 + l15];
#pragma unroll
    for (int kt = 0; kt < 2; ++kt)
      bwb[nt][kt] =
          *(const bfrag*)(WTb + (nt * 16 + l15) * 64 + kt * 32 + q * 8);
  }
  asm volatile("s_waitcnt vmcnt(0)" ::: "memory");

#pragma unroll
  for (int b = 0; b < 2; ++b) {
    const size_t rb = r0 + b * 64;
    // phase A: Y1 rows (wave-private, unroll 2 + packed convert)
    for (int e = 0; e < 32; e += 2) {
      int row = wr + e;
      f4v xv0 = *(const f4v*)&lds_x[b][row * 4];
      f4v xv1 = *(const f4v*)&lds_x[b][(row + 1) * 4];
      float a0 = b2, a1 = b2;
#pragma unroll
      for (int k = 0; k < 4; ++k) {
        a0 = fmaf(xv0[k], w2[k], a0);
        a1 = fmaf(xv1[k], w2[k], a1);
      }
      float z0 = tanh_fast(a0), z1 = tanh_fast(a1);
      unsigned p = cvt_pk_bf16(fmaf(A1c, z0, B1c), fmaf(A1c, z1, B1c));
      lds_y[row * 72 + lane] = (short)p;
      lds_y[(row + 1) * 72 + lane] = (short)(p >> 16);
    }

    // phase B: A-frags (own rows), store Y1, stats matmul
    bfrag af[2][2];
#pragma unroll
    for (int mt = 0; mt < 2; ++mt)
#pragma unroll
      for (int kt = 0; kt < 2; ++kt) {
        af[mt][kt] =
            *(const bfrag*)&lds_y[(wr + mt * 16 + l15) * 72 + kt * 32 + q * 8];
        *(bfrag*)(Y + (rb + wr + mt * 16 + l15) * 64 + kt * 32 + q * 8) =
            af[mt][kt];
      }
    facc acc2[2][4];
#pragma unroll
    for (int mt = 0; mt < 2; ++mt)
#pragma unroll
      for (int nt = 0; nt < 4; ++nt) {
        acc2[mt][nt][0] = bbv[nt]; acc2[mt][nt][1] = bbv[nt];
        acc2[mt][nt][2] = bbv[nt]; acc2[mt][nt][3] = bbv[nt];
      }
#pragma unroll
    for (int mt = 0; mt < 2; ++mt)
#pragma unroll
      for (int nt = 0; nt < 4; ++nt)
#pragma unroll
        for (int kt = 0; kt < 2; ++kt)
          acc2[mt][nt] = __builtin_amdgcn_mfma_f32_16x16x32_bf16(
              af[mt][kt], bwb[nt][kt], acc2[mt][nt], 0, 0, 0);
#pragma unroll
    for (int nt = 0; nt < 4; ++nt) {
      float s = 0.f, ss = 0.f;
#pragma unroll
      for (int mt = 0; mt < 2; ++mt)
#pragma unroll
        for (int i = 0; i < 4; ++i) {
          float z = tanh_fast(acc2[mt][nt][i]);
          s += z;
          ss = fmaf(z, z, ss);
        }
      s += __shfl_xor(s, 16); s += __shfl_xor(s, 32);
      ss += __shfl_xor(ss, 16); ss += __shfl_xor(ss, 32);
      if (q == 0) {
        if (b == 0) {
          red[wave][nt * 16 + l15] = s;
          red[wave][64 + nt * 16 + l15] = ss;
        } else {
          red[wave][nt * 16 + l15] += s;
          red[wave][64 + nt * 16 + l15] += ss;
        }
      }
    }
  }
  __syncthreads();
  atomicAdd(&Pb[(size_t)(blockIdx.x & (NBUCKET - 1)) * 128 + tid],
            red[0][tid] + red[1][tid]);
}

// K_mid: recompute Z_a = tanh(Y@WTa+ba), Ynew = BN(Z_a)+Y (in-place LDS),
// store Ynew; stats matmul with WTb -> bucket atomicAdd.
// 2 tiles/wave, both gld_lds-prefetched up-front (8 in-flight loads/wave).
__global__ __launch_bounds__(128) void k_mid(
    short* __restrict__ Y, const short* __restrict__ WTa,
    const float* __restrict__ ba, const float* __restrict__ ga,
    const float* __restrict__ bea, const float* __restrict__ sa,
    const short* __restrict__ WTb, const float* __restrict__ bb,
    float* __restrict__ Pb) {
  __shared__ __align__(16) short lds_y[2][64 * 64];
  __shared__ float red[2][128];

  const int tid = threadIdx.x;
  const int lane = tid & 63;
  const int wave = tid >> 6;
  const int l15 = lane & 15;
  const int q = lane >> 4;
  const int wr = wave * 32;
  const size_t r0 = (size_t)blockIdx.x * 128;

  // async prefetch of BOTH tiles (pre-swizzled global source)
  {
    const int srow = lane >> 3;
    const int cu = ((lane & 7) ^ srow) * 8;
#pragma unroll
    for (int b = 0; b < 2; ++b)
#pragma unroll
      for (int it = 0; it < 4; ++it)
        gld16(Y + (r0 + b * 64 + wr + it * 8 + srow) * 64 + cu,
              &lds_y[b][(wr + it * 8) * 64]);
  }

  float Av[4], Bv[4], bav[4];
#pragma unroll
  for (int nt = 0; nt < 4; ++nt) {
    int c = nt * 16 + l15;
    float mean = sa[c] * INV_B;
    float var = fmaf(-mean, mean, sa[64 + c] * INV_B);
    float A = ga[c] * rsqrtf(var + EPS);
    Av[nt] = A;
    Bv[nt] = fmaf(-A, mean, bea[c]);
    bav[nt] = ba[c];
  }
  bfrag bwa[4][2];
#pragma unroll
  for (int nt = 0; nt < 4; ++nt)
#pragma unroll
    for (int kt = 0; kt < 2; ++kt)
      bwa[nt][kt] =
          *(const bfrag*)(WTa + (nt * 16 + l15) * 64 + kt * 32 + q * 8);

  // drain staging (also drains the W/const loads — all needed now)
  asm volatile("s_waitcnt vmcnt(0)" ::: "memory");

#pragma unroll
  for (int b = 0; b < 2; ++b) {
    short* cur = &lds_y[b][0];
    const size_t rb = r0 + b * 64;

    // matmul1: recompute Z_a (bit-identical to producer's stats matmul)
    bfrag af[2][2];
#pragma unroll
    for (int mt = 0; mt < 2; ++mt)
#pragma unroll
      for (int kt = 0; kt < 2; ++kt)
        af[mt][kt] =
            *(const bfrag*)&cur[ysw(wr + mt * 16 + l15, kt * 32 + q * 8)];
    facc acc[2][4];
#pragma unroll
    for (int mt = 0; mt < 2; ++mt)
#pragma unroll
      for (int nt = 0; nt < 4; ++nt) {
        acc[mt][nt][0] = bav[nt]; acc[mt][nt][1] = bav[nt];
        acc[mt][nt][2] = bav[nt]; acc[mt][nt][3] = bav[nt];
      }
#pragma unroll
    for (int mt = 0; mt < 2; ++mt)
#pragma unroll
      for (int nt = 0; nt < 4; ++nt)
#pragma unroll
        for (int kt = 0; kt < 2; ++kt)
          acc[mt][nt] = __builtin_amdgcn_mfma_f32_16x16x32_bf16(
              af[mt][kt], bwa[nt][kt], acc[mt][nt], 0, 0, 0);

    // BN + residual, in-place (wave-private rows; packed converts)
#pragma unroll
    for (int mt = 0; mt < 2; ++mt)
#pragma unroll
      for (int nt = 0; nt < 4; ++nt) {
        int c = nt * 16 + l15;
        float A = Av[nt], Bc = Bv[nt];
        int rbr = wr + mt * 16 + q * 4;
        float v0 = fmaf(A, tanh_fast(acc[mt][nt][0]), Bc) +
                   bf2f(cur[ysw(rbr + 0, c)]);
        float v1 = fmaf(A, tanh_fast(acc[mt][nt][1]), Bc) +
                   bf2f(cur[ysw(rbr + 1, c)]);
        float v2 = fmaf(A, tanh_fast(acc[mt][nt][2]), Bc) +
                   bf2f(cur[ysw(rbr + 2, c)]);
        float v3 = fmaf(A, tanh_fast(acc[mt][nt][3]), Bc) +
                   bf2f(cur[ysw(rbr + 3, c)]);
        unsigned p01 = cvt_pk_bf16(v0, v1);
        unsigned p23 = cvt_pk_bf16(v2, v3);
        cur[ysw(rbr + 0, c)] = (short)p01;
        cur[ysw(rbr + 1, c)] = (short)(p01 >> 16);
        cur[ysw(rbr + 2, c)] = (short)p23;
        cur[ysw(rbr + 3, c)] = (short)(p23 >> 16);
      }

    // phase 4: reload own rows (now Ynew), store; stats matmul with late bwb
#pragma unroll
    for (int mt = 0; mt < 2; ++mt)
#pragma unroll
      for (int kt = 0; kt < 2; ++kt) {
        af[mt][kt] =
            *(const bfrag*)&cur[ysw(wr + mt * 16 + l15, kt * 32 + q * 8)];
        *(bfrag*)(Y + (rb + wr + mt * 16 + l15) * 64 + kt * 32 + q * 8) =
            af[mt][kt];
      }
    float bbv[4];
    bfrag bwb[4][2];
#pragma unroll
    for (int nt = 0; nt < 4; ++nt) {
      bbv[nt] = bb[nt * 16 + l15];
#pragma unroll
      for (int kt = 0; kt < 2; ++kt)
        bwb[nt][kt] =
            *(const bfrag*)(WTb + (nt * 16 + l15) * 64 + kt * 32 + q * 8);
    }
#pragma unroll
    for (int mt = 0; mt < 2; ++mt)
#pragma unroll
      for (int nt = 0; nt < 4; ++nt) {
        acc[mt][nt][0] = bbv[nt]; acc[mt][nt][1] = bbv[nt];
        acc[mt][nt][2] = bbv[nt]; acc[mt][nt][3] = bbv[nt];
      }
#pragma unroll
    for (int mt = 0; mt < 2; ++mt)
#pragma unroll
      for (int nt = 0; nt < 4; ++nt)
#pragma unroll
        for (int kt = 0; kt < 2; ++kt)
          acc[mt][nt] = __builtin_amdgcn_mfma_f32_16x16x32_bf16(
              af[mt][kt], bwb[nt][kt], acc[mt][nt], 0, 0, 0);
#pragma unroll
    for (int nt = 0; nt < 4; ++nt) {
      float s = 0.f, ss = 0.f;
#pragma unroll
      for (int mt = 0; mt < 2; ++mt)
#pragma unroll
        for (int i = 0; i < 4; ++i) {
          float z = tanh_fast(acc[mt][nt][i]);
          s += z;
          ss = fmaf(z, z, ss);
        }
      s += __shfl_xor(s, 16); s += __shfl_xor(s, 32);
      ss += __shfl_xor(ss, 16); ss += __shfl_xor(ss, 32);
      if (q == 0) {
        if (b == 0) {
          red[wave][nt * 16 + l15] = s;
          red[wave][64 + nt * 16 + l15] = ss;
        } else {
          red[wave][nt * 16 + l15] += s;
          red[wave][64 + nt * 16 + l15] += ss;
        }
      }
    }
  }
  __syncthreads();
  atomicAdd(&Pb[(size_t)(blockIdx.x & (NBUCKET - 1)) * 128 + tid],
            red[0][tid] + red[1][tid]);
}

// K_last: recompute Z5, Y5 = BN(Z5)+Y4 (in-place), out = Y5 @ Wout + bout.
// 2 tiles/wave, both prefetched up-front.
__global__ __launch_bounds__(128) void k_last(
    const short* __restrict__ Y, const short* __restrict__ WTa,
    const float* __restrict__ ba, const float* __restrict__ ga,
    const float* __restrict__ bea, const float* __restrict__ sa,
    const float* __restrict__ Wout, const float* __restrict__ bout,
    float* __restrict__ out) {
  __shared__ __align__(16) short lds_y[2][64 * 64];
  __shared__ float lds_wo[192];

  const int tid = threadIdx.x;
  const int lane = tid & 63;
  const int wave = tid >> 6;
  const int l15 = lane & 15;
  const int q = lane >> 4;
  const int wr = wave * 32;
  const size_t r0 = (size_t)blockIdx.x * 128;

  {
    const int srow = lane >> 3;
    const int cu = ((lane & 7) ^ srow) * 8;
#pragma unroll
    for (int b = 0; b < 2; ++b)
#pragma unroll
      for (int it = 0; it < 4; ++it)
        gld16(Y + (r0 + b * 64 + wr + it * 8 + srow) * 64 + cu,
              &lds_y[b][(wr + it * 8) * 64]);
  }

  for (int i = tid; i < 192; i += 128) lds_wo[i] = Wout[i];
  float Av[4], Bv[4], bav[4];
#pragma unroll
  for (int nt = 0; nt < 4; ++nt) {
    int c = nt * 16 + l15;
    float mean = sa[c] * INV_B;
    float var = fmaf(-mean, mean, sa[64 + c] * INV_B);
    float A = ga[c] * rsqrtf(var + EPS);
    Av[nt] = A;
    Bv[nt] = fmaf(-A, mean, bea[c]);
    bav[nt] = ba[c];
  }
  bfrag bwa[4][2];
#pragma unroll
  for (int nt = 0; nt < 4; ++nt)
#pragma unroll
    for (int kt = 0; kt < 2; ++kt)
      bwa[nt][kt] =
          *(const bfrag*)(WTa + (nt * 16 + l15) * 64 + kt * 32 + q * 8);
  float bo0 = bout[0], bo1 = bout[1], bo2 = bout[2];

  asm volatile("s_waitcnt vmcnt(0)" ::: "memory");
  __syncthreads();  // lds_wo visible to both waves

#pragma unroll
  for (int b = 0; b < 2; ++b) {
    short* cur = &lds_y[b][0];
    const size_t rb = r0 + b * 64;

    bfrag af[2][2];
#pragma unroll
    for (int mt = 0; mt < 2; ++mt)
#pragma unroll
      for (int kt = 0; kt < 2; ++kt)
        af[mt][kt] =
            *(const bfrag*)&cur[ysw(wr + mt * 16 + l15, kt * 32 + q * 8)];
    facc acc[2][4];
#pragma unroll
    for (int mt = 0; mt < 2; ++mt)
#pragma unroll
      for (int nt = 0; nt < 4; ++nt) {
        acc[mt][nt][0] = bav[nt]; acc[mt][nt][1] = bav[nt];
        acc[mt][nt][2] = bav[nt]; acc[mt][nt][3] = bav[nt];
      }
#pragma unroll
    for (int mt = 0; mt < 2; ++mt)
#pragma unroll
      for (int nt = 0; nt < 4; ++nt)
#pragma unroll
        for (int kt = 0; kt < 2; ++kt)
          acc[mt][nt] = __builtin_amdgcn_mfma_f32_16x16x32_bf16(
              af[mt][kt], bwa[nt][kt], acc[mt][nt], 0, 0, 0);
#pragma unroll
    for (int mt = 0; mt < 2; ++mt)
#pragma unroll
      for (int nt = 0; nt < 4; ++nt) {
        int c = nt * 16 + l15;
        float A = Av[nt], Bc = Bv[nt];
        int rbr = wr + mt * 16 + q * 4;
        float v0 = fmaf(A, tanh_fast(acc[mt][nt][0]), Bc) +
                   bf2f(cur[ysw(rbr + 0, c)]);
        float v1 = fmaf(A, tanh_fast(acc[mt][nt][1]), Bc) +
                   bf2f(cur[ysw(rbr + 1, c)]);
        float v2 = fmaf(A, tanh_fast(acc[mt][nt][2]), Bc) +
                   bf2f(cur[ysw(rbr + 2, c)]);
        float v3 = fmaf(A, tanh_fast(acc[mt][nt][3]), Bc) +
                   bf2f(cur[ysw(rbr + 3, c)]);
        unsigned p01 = cvt_pk_bf16(v0, v1);
        unsigned p23 = cvt_pk_bf16(v2, v3);
        cur[ysw(rbr + 0, c)] = (short)p01;
        cur[ysw(rbr + 1, c)] = (short)(p01 >> 16);
        cur[ysw(rbr + 2, c)] = (short)p23;
        cur[ysw(rbr + 3, c)] = (short)(p23 >> 16);
      }

    // epilogue (wave-private): lane pair (2r,2r+1) handles row wr+r
    {
      int row = wr + (lane >> 1);
      int cb = (lane & 1) * 32;
      float o0 = 0.f, o1 = 0.f, o2 = 0.f;
#pragma unroll
      for (int jc = 0; jc < 4; ++jc) {
        bfrag v = *(const bfrag*)&cur[ysw(row, cb + jc * 8)];
#pragma unroll
        for (int j = 0; j < 8; ++j) {
          float f = bf2f(v[j]);
          int jj = cb + jc * 8 + j;
          o0 = fmaf(f, lds_wo[jj * 3 + 0], o0);
          o1 = fmaf(f, lds_wo[jj * 3 + 1], o1);
          o2 = fmaf(f, lds_wo[jj * 3 + 2], o2);
        }
      }
      o0 += __shfl_xor(o0, 1);
      o1 += __shfl_xor(o1, 1);
      o2 += __shfl_xor(o2, 1);
      if ((lane & 1) == 0) {
        size_t ro = (rb + row) * 3;
        out[ro] = o0 + bo0;
        out[ro + 1] = o1 + bo1;
        out[ro + 2] = o2 + bo2;
      }
    }
  }
}

extern "C" void kernel_launch(void* const* d_in, const int* in_sizes, int n_in,
                              void* d_out, int out_size, void* d_ws,
                              size_t ws_size, hipStream_t stream) {
  (void)in_sizes; (void)n_in; (void)out_size; (void)ws_size;
  const float* x = (const float*)d_in[0];
  const float* bn0g = (const float*)d_in[1];
  const float* bn0b = (const float*)d_in[2];
  const float* W0 = (const float*)d_in[3];
  const float* b0 = (const float*)d_in[4];
  const float* gamma0 = (const float*)d_in[5];
  const float* beta0 = (const float*)d_in[6];
  const float* Wh = (const float*)d_in[7];
  const float* bh = (const float*)d_in[8];
  const float* gh = (const float*)d_in[9];
  const float* beh = (const float*)d_in[10];
  const float* Wout = (const float*)d_in[11];
  const float* bout = (const float*)d_in[12];
  float* out = (float*)d_out;

  char* ws = (char*)d_ws;
  short* Y = (short*)ws;                       // 1M x 64 bf16 = 128 MB
  const size_t YB = (size_t)NROWS * 64 * 2;
  // one contiguous zero-init region: [stats 648f][Pb 4 x 256 x 128 f]
  float* stats = (float*)(ws + YB);
  float* Sx = stats;
  float* S1 = stats + 8;
  float* S2 = stats + 136;
  float* S3 = stats + 264;
  float* S4 = stats + 392;
  float* S5 = stats + 520;
  float* Pb2 = stats + 648;
  float* Pb3 = Pb2 + NBUCKET * 128;
  float* Pb4 = Pb3 + NBUCKET * 128;
  float* Pb5 = Pb4 + NBUCKET * 128;
  const size_t zbytes = (648 + 4 * NBUCKET * 128) * sizeof(float);
  short* WT = (short*)(ws + YB + ((zbytes + 255) & ~(size_t)255));
  float* P = (float*)((char*)WT + 32768);  // plain partials (<=1 MB)

  hipMemsetAsync(stats, 0, zbytes, stream);
  k_stats_x<<<1024, 256, 0, stream>>>(x, Wh, WT, P);
  k_reduce<8><<<8, 256, 0, stream>>>(P, Sx, 128);
  k_stats_z1<<<2048, 256, 0, stream>>>(x, bn0g, bn0b, W0, b0, Sx, P);
  k_reduce<128><<<16, 256, 0, stream>>>(P, S1, 128);
  k_first<<<BIGGRID, 128, 0, stream>>>(x, bn0g, bn0b, W0, b0, gamma0, beta0,
                                       Sx, S1, WT, bh, Pb2, Y);
  k_reduce<128><<<16, 256, 0, stream>>>(Pb2, S2, 16);
  k_mid<<<BIGGRID, 128, 0, stream>>>(Y, WT, bh, gh, beh, S2, WT + 4096,
                                     bh + 64, Pb3);
  k_reduce<128><<<16, 256, 0, stream>>>(Pb3, S3, 16);
  k_mid<<<BIGGRID, 128, 0, stream>>>(Y, WT + 4096, bh + 64, gh + 64, beh + 64,
                                     S3, WT + 2 * 4096, bh + 128, Pb4);
  k_reduce<128><<<16, 256, 0, stream>>>(Pb4, S4, 16);
  k_mid<<<BIGGRID, 128, 0, stream>>>(Y, WT + 2 * 4096, bh + 128, gh + 128,
                                     beh + 128, S4, WT + 3 * 4096, bh + 192,
                                     Pb5);
  k_reduce<128><<<16, 256, 0, stream>>>(Pb5, S5, 16);
  k_last<<<BIGGRID, 128, 0, stream>>>(Y, WT + 3 * 4096, bh + 192, gh + 192,
                                      beh + 192, S5, Wout, bout, out);
}

// Round 14
// 485.142 us; speedup vs baseline: 1.0332x; 1.0332x over previous
//
#include <hip/hip_runtime.h>
#include <stdint.h>

// B = 1048576 rows, HID = 64. Residual MLP with training-mode BatchNorm.
// Recompute-fused layer kernels + bf16 activations (128 MB in d_ws).
// Round 18 = restore the measured-best state (R12 golden, 489.8 us).
// Thirteen rounds of structural variation (occupancy 19-50%, reg/LDS/async
// staging, 1-2 tiles/wave, pipelining, launch fusion) all return k_mid to
// ~89-90 us at ~2.3 TB/s mixed R+W — the recompute-fused algorithm's
// dependency-structure equilibrium on MI355X.
// HARD RULES from measurement:
//   (1) big kernels stay at VGPR <= 64; unified VGPR+AGPR budget binds
//       occupancy (R8/R9/R16: crossing it costs 30-50% occupancy).
//   (2) keep the 32-row wave (R13: 16-row waves -> HBM 1.4TB/s).
//   (3) atomic same-address RMW ~60ns serialized (R6): <=64 contenders max.
//   (4) NEVER __threadfence() in per-block hot paths (R11: 6.7x disaster).
//   (5) multi-tile waves blow the register budget (R16: VGPR 88, occ 19%).
// MFMA 16x16x32 bf16 layouts (verified gfx950 mappings):
//   A: row = lane&15, k = (lane>>4)*8 + j   (16B contiguous -> b128)
//   B: col = lane&15, k = (lane>>4)*8 + j   (load from W^T, row-major)
//   C/D: col = lane&15, row = (lane>>4)*4 + reg

#define NROWS 1048576
#define EPS 1e-5f
#define INV_B 9.5367431640625e-07f  // 1/2^20 exact
#define LOG2E2 2.885390081777927f   // 2*log2(e)
#define BIGGRID 16384               // 16384 blocks x 64 rows
#define NBUCKET 256

typedef __attribute__((ext_vector_type(8))) short bfrag;   // 8 bf16 = 4 VGPR
typedef __attribute__((ext_vector_type(4))) float facc;    // MFMA C/D
typedef __attribute__((ext_vector_type(4))) float f4v;
typedef unsigned int u32;

__device__ __forceinline__ float bf2f(short s) {
  union { unsigned u; float f; } v;
  v.u = ((unsigned)(unsigned short)s) << 16;
  return v.f;
}
__device__ __forceinline__ short f2bf(float f) {
  union { float f; unsigned u; } v;
  v.f = f;
  unsigned r = v.u + 0x7FFFu + ((v.u >> 16) & 1u);  // RNE
  return (short)(r >> 16);
}
// packed RNE f32->bf16x2 (identical rounding to f2bf, 1 instr for 2 elems)
__device__ __forceinline__ unsigned cvt_pk_bf16(float lo, float hi) {
  unsigned r;
  asm("v_cvt_pk_bf16_f32 %0, %1, %2" : "=v"(r) : "v"(lo), "v"(hi));
  return r;
}
// tanh = 1 - 2/(e^{2x}+1); v_exp + v_rcp, saturates correctly at +-inf
__device__ __forceinline__ float tanh_fast(float x) {
  float e = __builtin_amdgcn_exp2f(x * LOG2E2);
  return 1.f - 2.f * __builtin_amdgcn_rcpf(e + 1.f);
}

// ---------------- reduce: P[nb][W] -> atomicAdd into S[W] ----------------
template <int W>
__global__ __launch_bounds__(256) void k_reduce(const float* __restrict__ P,
                                                float* __restrict__ S,
                                                int rows_per_blk) {
  __shared__ float red[256];
  const int tid = threadIdx.x;
  const int col = tid % W;
  const int grp = tid / W;
  const int G = 256 / W;
  size_t r0 = (size_t)blockIdx.x * rows_per_blk;
  float s = 0.f;
  for (int r = grp; r < rows_per_blk; r += G) s += P[(r0 + r) * W + col];
  red[tid] = s;
  __syncthreads();
  if (tid < W) {
    float t = 0.f;
#pragma unroll 4
    for (int g = 0; g < G; ++g) t += red[g * W + tid];
    atomicAdd(&S[tid], t);
  }
}

// ---------------- small kernels ----------------

// Column sums/sumsq of x -> P[bid][8]. Blocks 0..63 also transpose Wh -> WT.
__global__ __launch_bounds__(256) void k_stats_x(const float* __restrict__ x,
                                                 const float* __restrict__ Wh,
                                                 short* __restrict__ WT,
                                                 float* __restrict__ P) {
  __shared__ float red[4][8];
  const int tid = threadIdx.x;
  const int wave = tid >> 6;
  const int bid = blockIdx.x;

  if (bid < 64) {  // folded k_prep: 64 blocks x 256 threads = 16384 elems
    int idx = bid * 256 + tid;
    int l = idx >> 12, rem = idx & 4095, k = rem >> 6, c = rem & 63;
    WT[l * 4096 + c * 64 + k] = f2bf(Wh[l * 4096 + k * 64 + c]);
  }

  size_t base = (size_t)bid * 1024 + tid;
  float s[4] = {0.f, 0.f, 0.f, 0.f}, q[4] = {0.f, 0.f, 0.f, 0.f};
#pragma unroll
  for (int it = 0; it < 4; ++it) {
    f4v v = *(const f4v*)(x + (base + (size_t)it * 256) * 4);
#pragma unroll
    for (int k = 0; k < 4; ++k) { s[k] += v[k]; q[k] = fmaf(v[k], v[k], q[k]); }
  }
#pragma unroll
  for (int off = 32; off > 0; off >>= 1) {
#pragma unroll
    for (int k = 0; k < 4; ++k) {
      s[k] += __shfl_xor(s[k], off);
      q[k] += __shfl_xor(q[k], off);
    }
  }
  if ((tid & 63) == 0) {
#pragma unroll
    for (int k = 0; k < 4; ++k) { red[wave][k] = s[k]; red[wave][4 + k] = q[k]; }
  }
  __syncthreads();
  if (tid < 8)
    P[bid * 8 + tid] = red[0][tid] + red[1][tid] + red[2][tid] + red[3][tid];
}

// Stats of z1 = tanh(bn0(x)@W0+b0) -> P[bid][128]. 2048 blocks, 128 rows/wave.
__global__ __launch_bounds__(256) void k_stats_z1(
    const float* __restrict__ x, const float* __restrict__ bn0g,
    const float* __restrict__ bn0b, const float* __restrict__ W0,
    const float* __restrict__ b0, const float* __restrict__ sx,
    float* __restrict__ P) {
  __shared__ float red[2][4][64];
  const int tid = threadIdx.x;
  const int lane = tid & 63;
  const int wave = tid >> 6;
  int gw = blockIdx.x * 4 + wave;
  float sc[4], sh[4];
#pragma unroll
  for (int k = 0; k < 4; ++k) {
    float mean = sx[k] * INV_B;
    float var = fmaf(-mean, mean, sx[4 + k] * INV_B);
    float rs = rsqrtf(var + EPS);
    sc[k] = bn0g[k] * rs;
    sh[k] = fmaf(-sc[k], mean, bn0b[k]);
  }
  // fold bn0 affine into the weight column: acc = b2 + sum_k x[k]*w2[k]
  float w2[4];
  float b2 = b0[lane];
#pragma unroll
  for (int k = 0; k < 4; ++k) {
    float w = W0[k * 64 + lane];
    w2[k] = sc[k] * w;
    b2 = fmaf(sh[k], w, b2);
  }
  float s = 0.f, q = 0.f;
  size_t r0 = (size_t)gw * 128;
  for (int r = 0; r < 128; ++r) {
    f4v xv = *(const f4v*)(x + (r0 + r) * 4);
    float acc = b2;
#pragma unroll
    for (int k = 0; k < 4; ++k) acc = fmaf(xv[k], w2[k], acc);
    float z = tanh_fast(acc);
    s += z;
    q = fmaf(z, z, q);
  }
  red[0][wave][lane] = s;
  red[1][wave][lane] = q;
  __syncthreads();
  if (tid < 128) {
    int which = tid >> 6, c = tid & 63;
    P[blockIdx.x * 128 + tid] = red[which][0][c] + red[which][1][c] +
                                red[which][2][c] + red[which][3][c];
  }
}

// ---------------- big fused kernels: 64 rows/block, 2 waves of 32 rows ----

// K_first: Y1 = BN(tanh(bn0(x)@W0+b0)), write Y1 bf16,
// partial stats of Z2 = tanh(Y1 @ W_hid0 + b_hid0) -> bucket atomicAdd
__global__ __launch_bounds__(128) void k_first(
    const float* __restrict__ x, const float* __restrict__ bn0g,
    const float* __restrict__ bn0b, const float* __restrict__ W0,
    const float* __restrict__ b0, const float* __restrict__ gamma0,
    const float* __restrict__ beta0, const float* __restrict__ sx,
    const float* __restrict__ s1, const short* __restrict__ WTb,
    const float* __restrict__ bb, float* __restrict__ Pb,
    short* __restrict__ Y) {
  __shared__ __align__(16) float lds_x[64 * 4];
  __shared__ __align__(16) short lds_y[64 * 72];
  __shared__ float red[2][128];

  const int tid = threadIdx.x;
  const int lane = tid & 63;
  const int wave = tid >> 6;
  const int l15 = lane & 15;
  const int q = lane >> 4;
  const int wr = wave * 32;
  const size_t r0 = (size_t)blockIdx.x * 64;

  // x staging load first (in flight during constant setup)
  f4v xp;
  if (lane < 32) xp = *(const f4v*)(x + (r0 + wr + lane) * 4);

  float sc0[4], sh0[4];
#pragma unroll
  for (int k = 0; k < 4; ++k) {
    float mean = sx[k] * INV_B;
    float var = fmaf(-mean, mean, sx[4 + k] * INV_B);
    float rs = rsqrtf(var + EPS);
    sc0[k] = bn0g[k] * rs;
    sh0[k] = fmaf(-sc0[k], mean, bn0b[k]);
  }
  // fold bn0 affine into weight column (same op order as k_stats_z1)
  float w2[4];
  float b2 = b0[lane];
#pragma unroll
  for (int k = 0; k < 4; ++k) {
    float w = W0[k * 64 + lane];
    w2[k] = sc0[k] * w;
    b2 = fmaf(sh0[k], w, b2);
  }
  float mean1 = s1[lane] * INV_B;
  float var1 = fmaf(-mean1, mean1, s1[64 + lane] * INV_B);
  float A1c = gamma0[lane] * rsqrtf(var1 + EPS);
  float B1c = fmaf(-A1c, mean1, beta0[lane]);
  if (lane < 32) *(f4v*)&lds_x[(wr + lane) * 4] = xp;

  // phase A: Y1 rows (wave-private, unroll 2 + packed convert)
  for (int e = 0; e < 32; e += 2) {
    int row = wr + e;
    f4v xv0 = *(const f4v*)&lds_x[row * 4];
    f4v xv1 = *(const f4v*)&lds_x[(row + 1) * 4];
    float a0 = b2, a1 = b2;
#pragma unroll
    for (int k = 0; k < 4; ++k) {
      a0 = fmaf(xv0[k], w2[k], a0);
      a1 = fmaf(xv1[k], w2[k], a1);
    }
    float z0 = tanh_fast(a0), z1 = tanh_fast(a1);
    unsigned p = cvt_pk_bf16(fmaf(A1c, z0, B1c), fmaf(A1c, z1, B1c));
    lds_y[row * 72 + lane] = (short)p;
    lds_y[(row + 1) * 72 + lane] = (short)(p >> 16);
  }

  // phase B: A-frags (own rows), store Y1, stats matmul
  bfrag af[2][2];
#pragma unroll
  for (int mt = 0; mt < 2; ++mt)
#pragma unroll
    for (int kt = 0; kt < 2; ++kt) {
      af[mt][kt] =
          *(const bfrag*)&lds_y[(wr + mt * 16 + l15) * 72 + kt * 32 + q * 8];
      *(bfrag*)(Y + (r0 + wr + mt * 16 + l15) * 64 + kt * 32 + q * 8) =
          af[mt][kt];
    }
  float bbv[4];
  bfrag bwb[4][2];
#pragma unroll
  for (int nt = 0; nt < 4; ++nt) {
    bbv[nt] = bb[nt * 16 + l15];
#pragma unroll
    for (int kt = 0; kt < 2; ++kt)
      bwb[nt][kt] =
          *(const bfrag*)(WTb + (nt * 16 + l15) * 64 + kt * 32 + q * 8);
  }
  facc acc2[2][4];
#pragma unroll
  for (int mt = 0; mt < 2; ++mt)
#pragma unroll
    for (int nt = 0; nt < 4; ++nt) {
      acc2[mt][nt][0] = bbv[nt]; acc2[mt][nt][1] = bbv[nt];
      acc2[mt][nt][2] = bbv[nt]; acc2[mt][nt][3] = bbv[nt];
    }
#pragma unroll
  for (int mt = 0; mt < 2; ++mt)
#pragma unroll
    for (int nt = 0; nt < 4; ++nt)
#pragma unroll
      for (int kt = 0; kt < 2; ++kt)
        acc2[mt][nt] = __builtin_amdgcn_mfma_f32_16x16x32_bf16(
            af[mt][kt], bwb[nt][kt], acc2[mt][nt], 0, 0, 0);
#pragma unroll
  for (int nt = 0; nt < 4; ++nt) {
    float s = 0.f, ss = 0.f;
#pragma unroll
    for (int mt = 0; mt < 2; ++mt)
#pragma unroll
      for (int i = 0; i < 4; ++i) {
        float z = tanh_fast(acc2[mt][nt][i]);
        s += z;
        ss = fmaf(z, z, ss);
      }
    s += __shfl_xor(s, 16); s += __shfl_xor(s, 32);
    ss += __shfl_xor(ss, 16); ss += __shfl_xor(ss, 32);
    if (q == 0) {
      red[wave][nt * 16 + l15] = s;
      red[wave][64 + nt * 16 + l15] = ss;
    }
  }
  __syncthreads();
  atomicAdd(&Pb[(size_t)(blockIdx.x & (NBUCKET - 1)) * 128 + tid],
            red[0][tid] + red[1][tid]);
}

// K_mid: recompute Z_a = tanh(Y@WTa+ba), Ynew = BN(Z_a)+Y (in-place LDS),
// store Ynew; stats matmul with WTb -> bucket atomicAdd.
__global__ __launch_bounds__(128) void k_mid(
    short* __restrict__ Y, const short* __restrict__ WTa,
    const float* __restrict__ ba, const float* __restrict__ ga,
    const float* __restrict__ bea, const float* __restrict__ sa,
    const short* __restrict__ WTb, const float* __restrict__ bb,
    float* __restrict__ Pb) {
  __shared__ __align__(16) short lds_y[64 * 72];
  __shared__ float red[2][128];

  const int tid = threadIdx.x;
  const int lane = tid & 63;
  const int wave = tid >> 6;
  const int l15 = lane & 15;
  const int q = lane >> 4;
  const int wr = wave * 32;
  const size_t r0 = (size_t)blockIdx.x * 64;
  const int srow = lane >> 3;       // 0..7
  const int sc8 = (lane & 7) * 8;   // staging col

  // staging loads FIRST (fly during constant setup)
  bfrag ld[4];
  {
    const size_t g = (r0 + wr + srow) * 64 + sc8;
#pragma unroll
    for (int it = 0; it < 4; ++it)
      ld[it] = *(const bfrag*)(Y + g + (size_t)it * 8 * 64);
  }

  float Av[4], Bv[4], bav[4];
#pragma unroll
  for (int nt = 0; nt < 4; ++nt) {
    int c = nt * 16 + l15;
    float mean = sa[c] * INV_B;
    float var = fmaf(-mean, mean, sa[64 + c] * INV_B);
    float A = ga[c] * rsqrtf(var + EPS);
    Av[nt] = A;
    Bv[nt] = fmaf(-A, mean, bea[c]);
    bav[nt] = ba[c];
  }
  bfrag bwa[4][2];
#pragma unroll
  for (int nt = 0; nt < 4; ++nt)
#pragma unroll
    for (int kt = 0; kt < 2; ++kt)
      bwa[nt][kt] =
          *(const bfrag*)(WTa + (nt * 16 + l15) * 64 + kt * 32 + q * 8);

  // stage own-wave rows (wave-private; lgkmcnt orders write->read)
#pragma unroll
  for (int it = 0; it < 4; ++it)
    *(bfrag*)&lds_y[(wr + it * 8 + srow) * 72 + sc8] = ld[it];

  // matmul1: recompute Z_a (bit-identical to producer's stats matmul)
  bfrag af[2][2];
#pragma unroll
  for (int mt = 0; mt < 2; ++mt)
#pragma unroll
    for (int kt = 0; kt < 2; ++kt)
      af[mt][kt] =
          *(const bfrag*)&lds_y[(wr + mt * 16 + l15) * 72 + kt * 32 + q * 8];
  facc acc[2][4];
#pragma unroll
  for (int mt = 0; mt < 2; ++mt)
#pragma unroll
    for (int nt = 0; nt < 4; ++nt) {
      acc[mt][nt][0] = bav[nt]; acc[mt][nt][1] = bav[nt];
      acc[mt][nt][2] = bav[nt]; acc[mt][nt][3] = bav[nt];
    }
#pragma unroll
  for (int mt = 0; mt < 2; ++mt)
#pragma unroll
    for (int nt = 0; nt < 4; ++nt)
#pragma unroll
      for (int kt = 0; kt < 2; ++kt)
        acc[mt][nt] = __builtin_amdgcn_mfma_f32_16x16x32_bf16(
            af[mt][kt], bwa[nt][kt], acc[mt][nt], 0, 0, 0);

  // BN + residual, in-place (wave-private rows; packed converts)
#pragma unroll
  for (int mt = 0; mt < 2; ++mt)
#pragma unroll
    for (int nt = 0; nt < 4; ++nt) {
      int c = nt * 16 + l15;
      float A = Av[nt], Bc = Bv[nt];
      int rb = wr + mt * 16 + q * 4;
      float v0 = fmaf(A, tanh_fast(acc[mt][nt][0]), Bc) +
                 bf2f(lds_y[(rb + 0) * 72 + c]);
      float v1 = fmaf(A, tanh_fast(acc[mt][nt][1]), Bc) +
                 bf2f(lds_y[(rb + 1) * 72 + c]);
      float v2 = fmaf(A, tanh_fast(acc[mt][nt][2]), Bc) +
                 bf2f(lds_y[(rb + 2) * 72 + c]);
      float v3 = fmaf(A, tanh_fast(acc[mt][nt][3]), Bc) +
                 bf2f(lds_y[(rb + 3) * 72 + c]);
      unsigned p01 = cvt_pk_bf16(v0, v1);
      unsigned p23 = cvt_pk_bf16(v2, v3);
      lds_y[(rb + 0) * 72 + c] = (short)p01;
      lds_y[(rb + 1) * 72 + c] = (short)(p01 >> 16);
      lds_y[(rb + 2) * 72 + c] = (short)p23;
      lds_y[(rb + 3) * 72 + c] = (short)(p23 >> 16);
    }

  // phase 4: reload own rows (now Ynew), store; stats matmul with late bwb
#pragma unroll
  for (int mt = 0; mt < 2; ++mt)
#pragma unroll
    for (int kt = 0; kt < 2; ++kt) {
      af[mt][kt] =
          *(const bfrag*)&lds_y[(wr + mt * 16 + l15) * 72 + kt * 32 + q * 8];
      *(bfrag*)(Y + (r0 + wr + mt * 16 + l15) * 64 + kt * 32 + q * 8) =
          af[mt][kt];
    }
  float bbv[4];
  bfrag bwb[4][2];
#pragma unroll
  for (int nt = 0; nt < 4; ++nt) {
    bbv[nt] = bb[nt * 16 + l15];
#pragma unroll
    for (int kt = 0; kt < 2; ++kt)
      bwb[nt][kt] =
          *(const bfrag*)(WTb + (nt * 16 + l15) * 64 + kt * 32 + q * 8);
  }
#pragma unroll
  for (int mt = 0; mt < 2; ++mt)
#pragma unroll
    for (int nt = 0; nt < 4; ++nt) {
      acc[mt][nt][0] = bbv[nt]; acc[mt][nt][1] = bbv[nt];
      acc[mt][nt][2] = bbv[nt]; acc[mt][nt][3] = bbv[nt];
    }
#pragma unroll
  for (int mt = 0; mt < 2; ++mt)
#pragma unroll
    for (int nt = 0; nt < 4; ++nt)
#pragma unroll
      for (int kt = 0; kt < 2; ++kt)
        acc[mt][nt] = __builtin_amdgcn_mfma_f32_16x16x32_bf16(
            af[mt][kt], bwb[nt][kt], acc[mt][nt], 0, 0, 0);
#pragma unroll
  for (int nt = 0; nt < 4; ++nt) {
    float s = 0.f, ss = 0.f;
#pragma unroll
    for (int mt = 0; mt < 2; ++mt)
#pragma unroll
      for (int i = 0; i < 4; ++i) {
        float z = tanh_fast(acc[mt][nt][i]);
        s += z;
        ss = fmaf(z, z, ss);
      }
    s += __shfl_xor(s, 16); s += __shfl_xor(s, 32);
    ss += __shfl_xor(ss, 16); ss += __shfl_xor(ss, 32);
    if (q == 0) {
      red[wave][nt * 16 + l15] = s;
      red[wave][64 + nt * 16 + l15] = ss;
    }
  }
  __syncthreads();
  atomicAdd(&Pb[(size_t)(blockIdx.x & (NBUCKET - 1)) * 128 + tid],
            red[0][tid] + red[1][tid]);
}

// K_last: recompute Z5, Y5 = BN(Z5)+Y4 (in-place), out = Y5 @ Wout + bout.
__global__ __launch_bounds__(128) void k_last(
    const short* __restrict__ Y, const short* __restrict__ WTa,
    const float* __restrict__ ba, const float* __restrict__ ga,
    const float* __restrict__ bea, const float* __restrict__ sa,
    const float* __restrict__ Wout, const float* __restrict__ bout,
    float* __restrict__ out) {
  __shared__ __align__(16) short lds_y[64 * 72];
  __shared__ float lds_wo[192];

  const int tid = threadIdx.x;
  const int lane = tid & 63;
  const int wave = tid >> 6;
  const int l15 = lane & 15;
  const int q = lane >> 4;
  const int wr = wave * 32;
  const size_t r0 = (size_t)blockIdx.x * 64;
  const int srow = lane >> 3;
  const int sc8 = (lane & 7) * 8;

  bfrag ld[4];
  {
    const size_t g = (r0 + wr + srow) * 64 + sc8;
#pragma unroll
    for (int it = 0; it < 4; ++it)
      ld[it] = *(const bfrag*)(Y + g + (size_t)it * 8 * 64);
  }

  for (int i = tid; i < 192; i += 128) lds_wo[i] = Wout[i];
  float Av[4], Bv[4], bav[4];
#pragma unroll
  for (int nt = 0; nt < 4; ++nt) {
    int c = nt * 16 + l15;
    float mean = sa[c] * INV_B;
    float var = fmaf(-mean, mean, sa[64 + c] * INV_B);
    float A = ga[c] * rsqrtf(var + EPS);
    Av[nt] = A;
    Bv[nt] = fmaf(-A, mean, bea[c]);
    bav[nt] = ba[c];
  }
  bfrag bwa[4][2];
#pragma unroll
  for (int nt = 0; nt < 4; ++nt)
#pragma unroll
    for (int kt = 0; kt < 2; ++kt)
      bwa[nt][kt] =
          *(const bfrag*)(WTa + (nt * 16 + l15) * 64 + kt * 32 + q * 8);
  float bo0 = bout[0], bo1 = bout[1], bo2 = bout[2];

#pragma unroll
  for (int it = 0; it < 4; ++it)
    *(bfrag*)&lds_y[(wr + it * 8 + srow) * 72 + sc8] = ld[it];
  __syncthreads();  // lds_wo visible to both waves

  bfrag af[2][2];
#pragma unroll
  for (int mt = 0; mt < 2; ++mt)
#pragma unroll
    for (int kt = 0; kt < 2; ++kt)
      af[mt][kt] =
          *(const bfrag*)&lds_y[(wr + mt * 16 + l15) * 72 + kt * 32 + q * 8];
  facc acc[2][4];
#pragma unroll
  for (int mt = 0; mt < 2; ++mt)
#pragma unroll
    for (int nt = 0; nt < 4; ++nt) {
      acc[mt][nt][0] = bav[nt]; acc[mt][nt][1] = bav[nt];
      acc[mt][nt][2] = bav[nt]; acc[mt][nt][3] = bav[nt];
    }
#pragma unroll
  for (int mt = 0; mt < 2; ++mt)
#pragma unroll
    for (int nt = 0; nt < 4; ++nt)
#pragma unroll
      for (int kt = 0; kt < 2; ++kt)
        acc[mt][nt] = __builtin_amdgcn_mfma_f32_16x16x32_bf16(
            af[mt][kt], bwa[nt][kt], acc[mt][nt], 0, 0, 0);
#pragma unroll
  for (int mt = 0; mt < 2; ++mt)
#pragma unroll
    for (int nt = 0; nt < 4; ++nt) {
      int c = nt * 16 + l15;
      float A = Av[nt], Bc = Bv[nt];
      int rb = wr + mt * 16 + q * 4;
      float v0 = fmaf(A, tanh_fast(acc[mt][nt][0]), Bc) +
                 bf2f(lds_y[(rb + 0) * 72 + c]);
      float v1 = fmaf(A, tanh_fast(acc[mt][nt][1]), Bc) +
                 bf2f(lds_y[(rb + 1) * 72 + c]);
      float v2 = fmaf(A, tanh_fast(acc[mt][nt][2]), Bc) +
                 bf2f(lds_y[(rb + 2) * 72 + c]);
      float v3 = fmaf(A, tanh_fast(acc[mt][nt][3]), Bc) +
                 bf2f(lds_y[(rb + 3) * 72 + c]);
      unsigned p01 = cvt_pk_bf16(v0, v1);
      unsigned p23 = cvt_pk_bf16(v2, v3);
      lds_y[(rb + 0) * 72 + c] = (short)p01;
      lds_y[(rb + 1) * 72 + c] = (short)(p01 >> 16);
      lds_y[(rb + 2) * 72 + c] = (short)p23;
      lds_y[(rb + 3) * 72 + c] = (short)(p23 >> 16);
    }

  // epilogue (wave-private): lane pair (2r,2r+1) handles row wr+r
  {
    int row = wr + (lane >> 1);
    int cb = (lane & 1) * 32;
    float o0 = 0.f, o1 = 0.f, o2 = 0.f;
#pragma unroll
    for (int jc = 0; jc < 4; ++jc) {
      bfrag v = *(const bfrag*)&lds_y[row * 72 + cb + jc * 8];
#pragma unroll
      for (int j = 0; j < 8; ++j) {
        float f = bf2f(v[j]);
        int jj = cb + jc * 8 + j;
        o0 = fmaf(f, lds_wo[jj * 3 + 0], o0);
        o1 = fmaf(f, lds_wo[jj * 3 + 1], o1);
        o2 = fmaf(f, lds_wo[jj * 3 + 2], o2);
      }
    }
    o0 += __shfl_xor(o0, 1);
    o1 += __shfl_xor(o1, 1);
    o2 += __shfl_xor(o2, 1);
    if ((lane & 1) == 0) {
      size_t ro = (r0 + row) * 3;
      out[ro] = o0 + bo0;
      out[ro + 1] = o1 + bo1;
      out[ro + 2] = o2 + bo2;
    }
  }
}

extern "C" void kernel_launch(void* const* d_in, const int* in_sizes, int n_in,
                              void* d_out, int out_size, void* d_ws,
                              size_t ws_size, hipStream_t stream) {
  (void)in_sizes; (void)n_in; (void)out_size; (void)ws_size;
  const float* x = (const float*)d_in[0];
  const float* bn0g = (const float*)d_in[1];
  const float* bn0b = (const float*)d_in[2];
  const float* W0 = (const float*)d_in[3];
  const float* b0 = (const float*)d_in[4];
  const float* gamma0 = (const float*)d_in[5];
  const float* beta0 = (const float*)d_in[6];
  const float* Wh = (const float*)d_in[7];
  const float* bh = (const float*)d_in[8];
  const float* gh = (const float*)d_in[9];
  const float* beh = (const float*)d_in[10];
  const float* Wout = (const float*)d_in[11];
  const float* bout = (const float*)d_in[12];
  float* out = (float*)d_out;

  char* ws = (char*)d_ws;
  short* Y = (short*)ws;                       // 1M x 64 bf16 = 128 MB
  const size_t YB = (size_t)NROWS * 64 * 2;
  // one contiguous zero-init region: [stats 648f][Pb 4 x 256 x 128 f]
  float* stats = (float*)(ws + YB);
  float* Sx = stats;
  float* S1 = stats + 8;
  float* S2 = stats + 136;
  float* S3 = stats + 264;
  float* S4 = stats + 392;
  float* S5 = stats + 520;
  float* Pb2 = stats + 648;
  float* Pb3 = Pb2 + NBUCKET * 128;
  float* Pb4 = Pb3 + NBUCKET * 128;
  float* Pb5 = Pb4 + NBUCKET * 128;
  const size_t zbytes = (648 + 4 * NBUCKET * 128) * sizeof(float);
  short* WT = (short*)(ws + YB + ((zbytes + 255) & ~(size_t)255));
  float* P = (float*)((char*)WT + 32768);  // plain partials (<=1 MB)

  hipMemsetAsync(stats, 0, zbytes, stream);
  k_stats_x<<<1024, 256, 0, stream>>>(x, Wh, WT, P);
  k_reduce<8><<<8, 256, 0, stream>>>(P, Sx, 128);
  k_stats_z1<<<2048, 256, 0, stream>>>(x, bn0g, bn0b, W0, b0, Sx, P);
  k_reduce<128><<<16, 256, 0, stream>>>(P, S1, 128);
  k_first<<<BIGGRID, 128, 0, stream>>>(x, bn0g, bn0b, W0, b0, gamma0, beta0,
                                       Sx, S1, WT, bh, Pb2, Y);
  k_reduce<128><<<16, 256, 0, stream>>>(Pb2, S2, 16);
  k_mid<<<BIGGRID, 128, 0, stream>>>(Y, WT, bh, gh, beh, S2, WT + 4096,
                                     bh + 64, Pb3);
  k_reduce<128><<<16, 256, 0, stream>>>(Pb3, S3, 16);
  k_mid<<<BIGGRID, 128, 0, stream>>>(Y, WT + 4096, bh + 64, gh + 64, beh + 64,
                                     S3, WT + 2 * 4096, bh + 128, Pb4);
  k_reduce<128><<<16, 256, 0, stream>>>(Pb4, S4, 16);
  k_mid<<<BIGGRID, 128, 0, stream>>>(Y, WT + 2 * 4096, bh + 128, gh + 128,
                                     beh + 128, S4, WT + 3 * 4096, bh + 192,
                                     Pb5);
  k_reduce<128><<<16, 256, 0, stream>>>(Pb5, S5, 16);
  k_last<<<BIGGRID, 128, 0, stream>>>(Y, WT + 3 * 4096, bh + 192, gh + 192,
                                      beh + 192, S5, Wout, bout, out);
}